// Round 1
// baseline (22114.360 us; speedup 1.0000x reference)
//
#include <hip/hip_runtime.h>

// Problem constants
#define NN 50000      // nodes
#define NE 800000     // edges
#define MP 50048      // padded rows = 391*128
#define GG 64         // graphs
#define HD 512        // hidden/feature dim
#define K2 1024       // fused K (agg | self)

typedef __attribute__((ext_vector_type(8))) short bf16x8;
typedef __attribute__((ext_vector_type(4))) float f32x4;

__device__ __forceinline__ unsigned short f2bf(float f) {
  unsigned u = __builtin_bit_cast(unsigned, f);
  u += 0x7fffu + ((u >> 16) & 1u);
  return (unsigned short)(u >> 16);
}
__device__ __forceinline__ float bf2f(unsigned short h) {
  unsigned u = ((unsigned)h) << 16;
  return __builtin_bit_cast(float, u);
}

__device__ __forceinline__ void g2l16(const void* g, void* l) {
  __builtin_amdgcn_global_load_lds(
      (const __attribute__((address_space(1))) unsigned int*)g,
      (__attribute__((address_space(3))) unsigned int*)l, 16, 0, 0);
}

// ---------------- weight transpose+convert: Wt[n][k], k<512 -> Wr[k][n], else Ws[k-512][n]
__global__ void wt_kernel(const float* __restrict__ Wr, const float* __restrict__ Ws,
                          unsigned short* __restrict__ Wt) {
  int idx = blockIdx.x * 256 + threadIdx.x;   // over 512*1024
  if (idx >= HD * K2) return;
  int n = idx >> 10;
  int k = idx & (K2 - 1);
  float v = (k < HD) ? Wr[k * HD + n] : Ws[(k - HD) * HD + n];
  Wt[idx] = f2bf(v);
}

// ---------------- fp32 -> bf16 convert with zero-padding past rows_in
__global__ void cvtpad_kernel(const float* __restrict__ in, unsigned short* __restrict__ out,
                              int rows_in, long long total4) {
  long long i = (long long)blockIdx.x * 256 + threadIdx.x;  // unit = 4 elements
  for (; i < total4; i += (long long)gridDim.x * 256) {
    int r = (int)((i * 4) >> 9);
    float4 v = make_float4(0.f, 0.f, 0.f, 0.f);
    if (r < rows_in) v = ((const float4*)in)[i];
    ushort4 o;
    o.x = f2bf(v.x); o.y = f2bf(v.y); o.z = f2bf(v.z); o.w = f2bf(v.w);
    ((ushort4*)out)[i] = o;
  }
}

// ---------------- edge scatter: agg[dst] += src row (bf16 read, fp32 atomic)
__global__ void scatter_kernel(const unsigned short* __restrict__ X,
                               const int* __restrict__ ei, float* __restrict__ agg) {
  int e = (blockIdx.x * 256 + threadIdx.x) >> 6;  // one edge per wave
  int lane = threadIdx.x & 63;
  int s = ei[e];
  int d = ei[NE + e];
  uint4 v = *(const uint4*)(X + (size_t)s * HD + lane * 8);
  float* dp = agg + (size_t)d * HD + lane * 8;
  atomicAdd(dp + 0, bf2f((unsigned short)(v.x & 0xffff)));
  atomicAdd(dp + 1, bf2f((unsigned short)(v.x >> 16)));
  atomicAdd(dp + 2, bf2f((unsigned short)(v.y & 0xffff)));
  atomicAdd(dp + 3, bf2f((unsigned short)(v.y >> 16)));
  atomicAdd(dp + 4, bf2f((unsigned short)(v.z & 0xffff)));
  atomicAdd(dp + 5, bf2f((unsigned short)(v.z >> 16)));
  atomicAdd(dp + 6, bf2f((unsigned short)(v.w & 0xffff)));
  atomicAdd(dp + 7, bf2f((unsigned short)(v.w >> 16)));
}

// ---------------- fused GEMM: H = relu([A0|A1] @ Wt^T + bias), all bf16 in, bf16 out
// A0,A1: [MP][512] bf16.  Wt: [512][1024] bf16 (row n = output col, contiguous K).
__global__ __launch_bounds__(256, 2) void gemm_kernel(
    const unsigned short* __restrict__ A0, const unsigned short* __restrict__ A1,
    const unsigned short* __restrict__ Wt, const float* __restrict__ bias,
    unsigned short* __restrict__ Hout) {
  __shared__ __align__(16) unsigned short Ads[128 * 64];
  __shared__ __align__(16) unsigned short Bds[128 * 64];

  const int tid = threadIdx.x;
  const int lane = tid & 63;
  const int wv = tid >> 6;   // 0..3
  const int wm = wv >> 1;    // 0..1
  const int wn = wv & 1;     // 0..1

  const int mt = blockIdx.x >> 2;   // 391 M-tiles
  const int nt = blockIdx.x & 3;    // 4 N-tiles
  const int row0 = mt * 128;
  const int col0 = nt * 128;

  f32x4 acc[4][4];
#pragma unroll
  for (int i = 0; i < 4; i++)
#pragma unroll
    for (int j = 0; j < 4; j++) acc[i][j] = (f32x4)(0.f);

  const int lr = lane >> 3;        // row within 8-row staging group
  const int lc = lane & 7;         // 16B chunk within 64-k row
  const int csw = lc ^ lr;         // pre-swizzled source chunk (T2 / m201 pattern)

  for (int kt = 0; kt < 16; ++kt) {
    const int k0 = kt * 64;
    const unsigned short* Asrc = (k0 < HD) ? A0 : A1;
    const int ka = k0 & (HD - 1);
#pragma unroll
    for (int it = 0; it < 4; ++it) {
      int r0 = (it * 4 + wv) * 8;
      g2l16(Asrc + (size_t)(row0 + r0 + lr) * HD + ka + csw * 8, &Ads[r0 * 64]);
    }
#pragma unroll
    for (int it = 0; it < 4; ++it) {
      int r0 = (it * 4 + wv) * 8;
      g2l16(Wt + (size_t)(col0 + r0 + lr) * K2 + k0 + csw * 8, &Bds[r0 * 64]);
    }
    __syncthreads();
#pragma unroll
    for (int kk = 0; kk < 2; ++kk) {
      bf16x8 af[4], bfr[4];
#pragma unroll
      for (int m = 0; m < 4; m++) {
        int r = wm * 64 + m * 16 + (lane & 15);
        int ck = (kk * 4 + (lane >> 4)) ^ (r & 7);
        af[m] = *(const bf16x8*)&Ads[r * 64 + ck * 8];
      }
#pragma unroll
      for (int n = 0; n < 4; n++) {
        int r = wn * 64 + n * 16 + (lane & 15);
        int ck = (kk * 4 + (lane >> 4)) ^ (r & 7);
        bfr[n] = *(const bf16x8*)&Bds[r * 64 + ck * 8];
      }
#pragma unroll
      for (int m = 0; m < 4; m++)
#pragma unroll
        for (int n = 0; n < 4; n++)
          acc[m][n] = __builtin_amdgcn_mfma_f32_16x16x32_bf16(af[m], bfr[n], acc[m][n], 0, 0, 0);
    }
    __syncthreads();
  }

#pragma unroll
  for (int n = 0; n < 4; n++) {
    int c = col0 + wn * 64 + n * 16 + (lane & 15);
    float bv = bias[c];
#pragma unroll
    for (int m = 0; m < 4; m++) {
      int rbase = row0 + wm * 64 + m * 16 + (lane >> 4) * 4;
#pragma unroll
      for (int r = 0; r < 4; r++) {
        float v = acc[m][n][r] + bv;
        v = v > 0.f ? v : 0.f;
        Hout[(size_t)(rbase + r) * HD + c] = f2bf(v);
      }
    }
  }
}

// ---------------- mean-pool partial sums (batch is sorted; binary search boundaries)
__device__ __forceinline__ int lbound(const int* b, int v) {
  int lo = 0, hi = NN;
  while (lo < hi) { int m = (lo + hi) >> 1; if (b[m] < v) lo = m + 1; else hi = m; }
  return lo;
}

__global__ void pool_kernel(const unsigned short* __restrict__ H, const int* __restrict__ batch,
                            float* __restrict__ pooled) {
  int b = blockIdx.x;          // 64 graphs * 2 col-halves * 8 row-chunks
  int g = b >> 4;
  int half = (b >> 3) & 1;
  int chunk = b & 7;
  int col = half * 256 + threadIdx.x;
  int start = lbound(batch, g);
  int end = lbound(batch, g + 1);
  int len = end - start;
  int r0 = start + (int)(((long long)len * chunk) >> 3);
  int r1 = start + (int)(((long long)len * (chunk + 1)) >> 3);
  float s = 0.f;
  for (int r = r0; r < r1; r++) s += bf2f(H[(size_t)r * HD + col]);
  atomicAdd(&pooled[g * HD + col], s);
}

// ---------------- classifier: out[g][c] = relu(pooled/cnt) @ Wl + bl
__global__ void final_kernel(const float* __restrict__ pooled, const int* __restrict__ batch,
                             const float* __restrict__ Wl, const float* __restrict__ bl,
                             float* __restrict__ out) {
  int g = blockIdx.x;
  int t = threadIdx.x;   // 256
  int lane = t & 63, wv = t >> 6;
  int start = lbound(batch, g);
  int end = lbound(batch, g + 1);
  float cnt = (float)(end - start);
  if (cnt < 1.f) cnt = 1.f;
  float a[10];
#pragma unroll
  for (int c = 0; c < 10; c++) a[c] = 0.f;
  for (int n = t; n < HD; n += 256) {
    float p = pooled[g * HD + n] / cnt;
    p = p > 0.f ? p : 0.f;
#pragma unroll
    for (int c = 0; c < 10; c++) a[c] += p * Wl[n * 10 + c];
  }
  __shared__ float red[10][4];
#pragma unroll
  for (int c = 0; c < 10; c++) {
    float v = a[c];
#pragma unroll
    for (int off = 32; off >= 1; off >>= 1) v += __shfl_down(v, off);
    if (lane == 0) red[c][wv] = v;
  }
  __syncthreads();
  if (t < 10) out[g * 10 + t] = red[t][0] + red[t][1] + red[t][2] + red[t][3] + bl[t];
}

extern "C" void kernel_launch(void* const* d_in, const int* in_sizes, int n_in,
                              void* d_out, int out_size, void* d_ws, size_t ws_size,
                              hipStream_t stream) {
  const float* x   = (const float*)d_in[0];
  const int* ei    = (const int*)d_in[1];
  const int* batch = (const int*)d_in[2];
  const float* Wr0 = (const float*)d_in[3];
  const float* br0 = (const float*)d_in[4];
  const float* Ws0 = (const float*)d_in[5];
  const float* Wr1 = (const float*)d_in[6];
  const float* br1 = (const float*)d_in[7];
  const float* Ws1 = (const float*)d_in[8];
  const float* Wl  = (const float*)d_in[9];
  const float* bl  = (const float*)d_in[10];
  float* out = (float*)d_out;

  char* ws = (char*)d_ws;
  size_t off = 0;
  auto alloc = [&](size_t bytes) { char* p = ws + off; off += (bytes + 255) & ~255ULL; return p; };
  unsigned short* xb   = (unsigned short*)alloc((size_t)MP * HD * 2);
  unsigned short* h0   = (unsigned short*)alloc((size_t)MP * HD * 2);
  unsigned short* aggb = (unsigned short*)alloc((size_t)MP * HD * 2);
  float* agg           = (float*)alloc((size_t)MP * HD * 4);
  unsigned short* Wt0  = (unsigned short*)alloc((size_t)HD * K2 * 2);
  unsigned short* Wt1  = (unsigned short*)alloc((size_t)HD * K2 * 2);
  float* pooled        = (float*)alloc((size_t)GG * HD * 4);
  unsigned short* h1 = xb;  // reuse: xb dead after GEMM1 inputs consumed... (used by GEMM1 only)

  const long long totMP4 = (long long)MP * HD / 4;

  wt_kernel<<<2048, 256, 0, stream>>>(Wr0, Ws0, Wt0);
  wt_kernel<<<2048, 256, 0, stream>>>(Wr1, Ws1, Wt1);
  cvtpad_kernel<<<2048, 256, 0, stream>>>(x, xb, NN, totMP4);

  hipMemsetAsync(agg, 0, (size_t)MP * HD * 4, stream);
  scatter_kernel<<<NE / 4, 256, 0, stream>>>(xb, ei, agg);
  cvtpad_kernel<<<2048, 256, 0, stream>>>(agg, aggb, MP, totMP4);
  gemm_kernel<<<391 * 4, 256, 0, stream>>>(aggb, xb, Wt0, br0, h0);

  hipMemsetAsync(agg, 0, (size_t)MP * HD * 4, stream);
  scatter_kernel<<<NE / 4, 256, 0, stream>>>(h0, ei, agg);
  cvtpad_kernel<<<2048, 256, 0, stream>>>(agg, aggb, MP, totMP4);
  gemm_kernel<<<391 * 4, 256, 0, stream>>>(aggb, h0, Wt1, br1, h1);

  hipMemsetAsync(pooled, 0, (size_t)GG * HD * 4, stream);
  pool_kernel<<<GG * 16, 256, 0, stream>>>(h1, batch, pooled);
  final_kernel<<<GG, 256, 0, stream>>>(pooled, batch, Wl, bl, out);
}

// Round 2
// 803.137 us; speedup vs baseline: 27.5350x; 27.5350x over previous
//
#include <hip/hip_runtime.h>

// Problem constants
#define NN 50000      // nodes
#define NE 800000     // edges
#define MP 50048      // padded rows = 391*128
#define GG 64         // graphs
#define HD 512        // hidden/feature dim
#define K2 1024       // fused K (agg | self)

typedef __attribute__((ext_vector_type(8))) short bf16x8;
typedef __attribute__((ext_vector_type(4))) float f32x4;

__device__ __forceinline__ unsigned short f2bf(float f) {
  unsigned u = __builtin_bit_cast(unsigned, f);
  u += 0x7fffu + ((u >> 16) & 1u);
  return (unsigned short)(u >> 16);
}
__device__ __forceinline__ float bf2f(unsigned short h) {
  unsigned u = ((unsigned)h) << 16;
  return __builtin_bit_cast(float, u);
}

__device__ __forceinline__ void g2l16(const void* g, void* l) {
  __builtin_amdgcn_global_load_lds(
      (const __attribute__((address_space(1))) unsigned int*)g,
      (__attribute__((address_space(3))) unsigned int*)l, 16, 0, 0);
}

// ---------------- weight transpose+convert: Wt[n][k], k<512 -> Wr[k][n], else Ws[k-512][n]
__global__ void wt_kernel(const float* __restrict__ Wr, const float* __restrict__ Ws,
                          unsigned short* __restrict__ Wt) {
  int idx = blockIdx.x * 256 + threadIdx.x;   // over 512*1024
  if (idx >= HD * K2) return;
  int n = idx >> 10;
  int k = idx & (K2 - 1);
  float v = (k < HD) ? Wr[k * HD + n] : Ws[(k - HD) * HD + n];
  Wt[idx] = f2bf(v);
}

// ---------------- fp32 -> bf16 convert with zero-padding past rows_in
__global__ void cvtpad_kernel(const float* __restrict__ in, unsigned short* __restrict__ out,
                              int rows_in, long long total4) {
  long long i = (long long)blockIdx.x * 256 + threadIdx.x;  // unit = 4 elements
  for (; i < total4; i += (long long)gridDim.x * 256) {
    int r = (int)((i * 4) >> 9);
    float4 v = make_float4(0.f, 0.f, 0.f, 0.f);
    if (r < rows_in) v = ((const float4*)in)[i];
    ushort4 o;
    o.x = f2bf(v.x); o.y = f2bf(v.y); o.z = f2bf(v.z); o.w = f2bf(v.w);
    ((ushort4*)out)[i] = o;
  }
}

// ---------------- CSR build: histogram, scan, fill
__global__ void hist_kernel(const int* __restrict__ ei, int* __restrict__ deg) {
  int i = blockIdx.x * 256 + threadIdx.x;
  if (i < NE) atomicAdd(&deg[ei[NE + i]], 1);
}

// single block, 1024 threads: exclusive scan of deg[0..NN) -> row_ptr, cursor
__global__ __launch_bounds__(1024) void scan_kernel(const int* __restrict__ deg,
                                                    int* __restrict__ row_ptr,
                                                    int* __restrict__ cursor) {
  __shared__ int part[1024];
  const int CH = (NN + 1023) / 1024;  // 49
  int t = threadIdx.x;
  int b0 = t * CH;
  int s = 0;
  for (int j = 0; j < CH; j++) { int i = b0 + j; if (i < NN) s += deg[i]; }
  part[t] = s;
  __syncthreads();
  for (int off = 1; off < 1024; off <<= 1) {
    int v = (t >= off) ? part[t - off] : 0;
    __syncthreads();
    part[t] += v;
    __syncthreads();
  }
  int run = (t == 0) ? 0 : part[t - 1];
  for (int j = 0; j < CH; j++) {
    int i = b0 + j;
    if (i < NN) { row_ptr[i] = run; cursor[i] = run; run += deg[i]; }
  }
  if (t == 1023) row_ptr[NN] = run;
}

__global__ void fill_kernel(const int* __restrict__ ei, int* __restrict__ cursor,
                            int* __restrict__ col) {
  int i = blockIdx.x * 256 + threadIdx.x;
  if (i < NE) {
    int d = ei[NE + i];
    int p = atomicAdd(&cursor[d], 1);
    col[p] = ei[i];
  }
}

// ---------------- gather aggregation: out[n] = sum_{c in N(n)} X[c]  (bf16 in/out, fp32 acc)
// one wave per output row; lane covers 8 contiguous columns (64*8 = 512)
__global__ __launch_bounds__(256) void gather_kernel(const unsigned short* __restrict__ X,
                                                     const int* __restrict__ row_ptr,
                                                     const int* __restrict__ col,
                                                     unsigned short* __restrict__ out) {
  int w = (blockIdx.x * 256 + threadIdx.x) >> 6;  // wave id = output row
  int lane = threadIdx.x & 63;
  if (w >= MP) return;
  float a0 = 0.f, a1 = 0.f, a2 = 0.f, a3 = 0.f, a4 = 0.f, a5 = 0.f, a6 = 0.f, a7 = 0.f;
  if (w < NN) {
    int r0 = row_ptr[w], r1 = row_ptr[w + 1];
    for (int base = r0; base < r1; base += 64) {
      int idx = base + lane;
      int myc = (idx < r1) ? col[idx] : 0;
      int cnt = min(64, r1 - base);
      #pragma unroll 4
      for (int j = 0; j < cnt; j++) {
        int c = __shfl(myc, j);
        uint4 v = *(const uint4*)(X + (size_t)c * HD + lane * 8);
        a0 += bf2f((unsigned short)(v.x & 0xffff));
        a1 += bf2f((unsigned short)(v.x >> 16));
        a2 += bf2f((unsigned short)(v.y & 0xffff));
        a3 += bf2f((unsigned short)(v.y >> 16));
        a4 += bf2f((unsigned short)(v.z & 0xffff));
        a5 += bf2f((unsigned short)(v.z >> 16));
        a6 += bf2f((unsigned short)(v.w & 0xffff));
        a7 += bf2f((unsigned short)(v.w >> 16));
      }
    }
  }
  uint4 o;
  o.x = ((unsigned)f2bf(a1) << 16) | f2bf(a0);
  o.y = ((unsigned)f2bf(a3) << 16) | f2bf(a2);
  o.z = ((unsigned)f2bf(a5) << 16) | f2bf(a4);
  o.w = ((unsigned)f2bf(a7) << 16) | f2bf(a6);
  *(uint4*)(out + (size_t)w * HD + lane * 8) = o;
}

// ---------------- fused GEMM: H = relu([A0|A1] @ Wt^T + bias), all bf16 in, bf16 out
// A0,A1: [MP][512] bf16.  Wt: [512][1024] bf16 (row n = output col, contiguous K).
__global__ __launch_bounds__(256, 2) void gemm_kernel(
    const unsigned short* __restrict__ A0, const unsigned short* __restrict__ A1,
    const unsigned short* __restrict__ Wt, const float* __restrict__ bias,
    unsigned short* __restrict__ Hout) {
  __shared__ __align__(16) unsigned short Ads[128 * 64];
  __shared__ __align__(16) unsigned short Bds[128 * 64];

  const int tid = threadIdx.x;
  const int lane = tid & 63;
  const int wv = tid >> 6;   // 0..3
  const int wm = wv >> 1;    // 0..1
  const int wn = wv & 1;     // 0..1

  const int mt = blockIdx.x >> 2;   // 391 M-tiles
  const int nt = blockIdx.x & 3;    // 4 N-tiles
  const int row0 = mt * 128;
  const int col0 = nt * 128;

  f32x4 acc[4][4];
#pragma unroll
  for (int i = 0; i < 4; i++)
#pragma unroll
    for (int j = 0; j < 4; j++) acc[i][j] = (f32x4)(0.f);

  const int lr = lane >> 3;        // row within 8-row staging group
  const int lc = lane & 7;         // 16B chunk within 64-k row
  const int csw = lc ^ lr;         // pre-swizzled source chunk (T2 / m201 pattern)

  for (int kt = 0; kt < 16; ++kt) {
    const int k0 = kt * 64;
    const unsigned short* Asrc = (k0 < HD) ? A0 : A1;
    const int ka = k0 & (HD - 1);
#pragma unroll
    for (int it = 0; it < 4; ++it) {
      int r0 = (it * 4 + wv) * 8;
      g2l16(Asrc + (size_t)(row0 + r0 + lr) * HD + ka + csw * 8, &Ads[r0 * 64]);
    }
#pragma unroll
    for (int it = 0; it < 4; ++it) {
      int r0 = (it * 4 + wv) * 8;
      g2l16(Wt + (size_t)(col0 + r0 + lr) * K2 + k0 + csw * 8, &Bds[r0 * 64]);
    }
    __syncthreads();
#pragma unroll
    for (int kk = 0; kk < 2; ++kk) {
      bf16x8 af[4], bfr[4];
#pragma unroll
      for (int m = 0; m < 4; m++) {
        int r = wm * 64 + m * 16 + (lane & 15);
        int ck = (kk * 4 + (lane >> 4)) ^ (r & 7);
        af[m] = *(const bf16x8*)&Ads[r * 64 + ck * 8];
      }
#pragma unroll
      for (int n = 0; n < 4; n++) {
        int r = wn * 64 + n * 16 + (lane & 15);
        int ck = (kk * 4 + (lane >> 4)) ^ (r & 7);
        bfr[n] = *(const bf16x8*)&Bds[r * 64 + ck * 8];
      }
#pragma unroll
      for (int m = 0; m < 4; m++)
#pragma unroll
        for (int n = 0; n < 4; n++)
          acc[m][n] = __builtin_amdgcn_mfma_f32_16x16x32_bf16(af[m], bfr[n], acc[m][n], 0, 0, 0);
    }
    __syncthreads();
  }

#pragma unroll
  for (int n = 0; n < 4; n++) {
    int c = col0 + wn * 64 + n * 16 + (lane & 15);
    float bv = bias[c];
#pragma unroll
    for (int m = 0; m < 4; m++) {
      int rbase = row0 + wm * 64 + m * 16 + (lane >> 4) * 4;
#pragma unroll
      for (int r = 0; r < 4; r++) {
        float v = acc[m][n][r] + bv;
        v = v > 0.f ? v : 0.f;
        Hout[(size_t)(rbase + r) * HD + c] = f2bf(v);
      }
    }
  }
}

// ---------------- mean-pool partial sums (batch is sorted; binary search boundaries)
__device__ __forceinline__ int lbound(const int* b, int v) {
  int lo = 0, hi = NN;
  while (lo < hi) { int m = (lo + hi) >> 1; if (b[m] < v) lo = m + 1; else hi = m; }
  return lo;
}

__global__ void pool_kernel(const unsigned short* __restrict__ H, const int* __restrict__ batch,
                            float* __restrict__ pooled) {
  int b = blockIdx.x;          // 64 graphs * 2 col-halves * 8 row-chunks
  int g = b >> 4;
  int half = (b >> 3) & 1;
  int chunk = b & 7;
  int col = half * 256 + threadIdx.x;
  int start = lbound(batch, g);
  int end = lbound(batch, g + 1);
  int len = end - start;
  int r0 = start + (int)(((long long)len * chunk) >> 3);
  int r1 = start + (int)(((long long)len * (chunk + 1)) >> 3);
  float s = 0.f;
  for (int r = r0; r < r1; r++) s += bf2f(H[(size_t)r * HD + col]);
  atomicAdd(&pooled[g * HD + col], s);
}

// ---------------- classifier: out[g][c] = relu(pooled/cnt) @ Wl + bl
__global__ void final_kernel(const float* __restrict__ pooled, const int* __restrict__ batch,
                             const float* __restrict__ Wl, const float* __restrict__ bl,
                             float* __restrict__ out) {
  int g = blockIdx.x;
  int t = threadIdx.x;   // 256
  int lane = t & 63, wv = t >> 6;
  int start = lbound(batch, g);
  int end = lbound(batch, g + 1);
  float cnt = (float)(end - start);
  if (cnt < 1.f) cnt = 1.f;
  float a[10];
#pragma unroll
  for (int c = 0; c < 10; c++) a[c] = 0.f;
  for (int n = t; n < HD; n += 256) {
    float p = pooled[g * HD + n] / cnt;
    p = p > 0.f ? p : 0.f;
#pragma unroll
    for (int c = 0; c < 10; c++) a[c] += p * Wl[n * 10 + c];
  }
  __shared__ float red[10][4];
#pragma unroll
  for (int c = 0; c < 10; c++) {
    float v = a[c];
#pragma unroll
    for (int off = 32; off >= 1; off >>= 1) v += __shfl_down(v, off);
    if (lane == 0) red[c][wv] = v;
  }
  __syncthreads();
  if (t < 10) out[g * 10 + t] = red[t][0] + red[t][1] + red[t][2] + red[t][3] + bl[t];
}

extern "C" void kernel_launch(void* const* d_in, const int* in_sizes, int n_in,
                              void* d_out, int out_size, void* d_ws, size_t ws_size,
                              hipStream_t stream) {
  const float* x   = (const float*)d_in[0];
  const int* ei    = (const int*)d_in[1];
  const int* batch = (const int*)d_in[2];
  const float* Wr0 = (const float*)d_in[3];
  const float* br0 = (const float*)d_in[4];
  const float* Ws0 = (const float*)d_in[5];
  const float* Wr1 = (const float*)d_in[6];
  const float* br1 = (const float*)d_in[7];
  const float* Ws1 = (const float*)d_in[8];
  const float* Wl  = (const float*)d_in[9];
  const float* bl  = (const float*)d_in[10];
  float* out = (float*)d_out;

  char* ws = (char*)d_ws;
  size_t off = 0;
  auto alloc = [&](size_t bytes) { char* p = ws + off; off += (bytes + 255) & ~255ULL; return p; };
  unsigned short* xb   = (unsigned short*)alloc((size_t)MP * HD * 2);
  unsigned short* h0   = (unsigned short*)alloc((size_t)MP * HD * 2);
  unsigned short* aggb = (unsigned short*)alloc((size_t)MP * HD * 2);
  unsigned short* Wt0  = (unsigned short*)alloc((size_t)HD * K2 * 2);
  unsigned short* Wt1  = (unsigned short*)alloc((size_t)HD * K2 * 2);
  float* pooled        = (float*)alloc((size_t)GG * HD * 4);
  int* deg             = (int*)alloc((size_t)NN * 4);
  int* row_ptr         = (int*)alloc((size_t)(NN + 1) * 4);
  int* cursor          = (int*)alloc((size_t)NN * 4);
  int* col             = (int*)alloc((size_t)NE * 4);
  unsigned short* h1 = xb;  // reuse: xb dead after GEMM1 consumes it

  const long long totMP4 = (long long)MP * HD / 4;

  // CSR build
  hipMemsetAsync(deg, 0, (size_t)NN * 4, stream);
  hist_kernel<<<(NE + 255) / 256, 256, 0, stream>>>(ei, deg);
  scan_kernel<<<1, 1024, 0, stream>>>(deg, row_ptr, cursor);
  fill_kernel<<<(NE + 255) / 256, 256, 0, stream>>>(ei, cursor, col);

  // weights + input conversion
  wt_kernel<<<2048, 256, 0, stream>>>(Wr0, Ws0, Wt0);
  wt_kernel<<<2048, 256, 0, stream>>>(Wr1, Ws1, Wt1);
  cvtpad_kernel<<<2048, 256, 0, stream>>>(x, xb, NN, totMP4);

  // layer 0
  gather_kernel<<<MP / 4, 256, 0, stream>>>(xb, row_ptr, col, aggb);
  gemm_kernel<<<391 * 4, 256, 0, stream>>>(aggb, xb, Wt0, br0, h0);

  // layer 1
  gather_kernel<<<MP / 4, 256, 0, stream>>>(h0, row_ptr, col, aggb);
  gemm_kernel<<<391 * 4, 256, 0, stream>>>(aggb, h0, Wt1, br1, h1);

  // pool + classify
  hipMemsetAsync(pooled, 0, (size_t)GG * HD * 4, stream);
  pool_kernel<<<GG * 16, 256, 0, stream>>>(h1, batch, pooled);
  final_kernel<<<GG, 256, 0, stream>>>(pooled, batch, Wl, bl, out);
}

// Round 3
// 685.272 us; speedup vs baseline: 32.2709x; 1.1720x over previous
//
#include <hip/hip_runtime.h>

// Problem constants
#define NN 50000      // nodes
#define NE 800000     // edges
#define MP 50048      // padded rows = 391*128
#define GG 64         // graphs
#define HD 512        // hidden/feature dim
#define K2 1024       // fused K (agg | self)
#define SCAN_BLKS 196 // ceil(50000/256)

typedef __attribute__((ext_vector_type(8))) short bf16x8;
typedef __attribute__((ext_vector_type(4))) float f32x4;

__device__ __forceinline__ unsigned short f2bf(float f) {
  unsigned u = __builtin_bit_cast(unsigned, f);
  u += 0x7fffu + ((u >> 16) & 1u);
  return (unsigned short)(u >> 16);
}
__device__ __forceinline__ float bf2f(unsigned short h) {
  unsigned u = ((unsigned)h) << 16;
  return __builtin_bit_cast(float, u);
}

__device__ __forceinline__ void g2l16(const void* g, void* l) {
  __builtin_amdgcn_global_load_lds(
      (const __attribute__((address_space(1))) unsigned int*)g,
      (__attribute__((address_space(3))) unsigned int*)l, 16, 0, 0);
}

// ---------------- weight transpose+convert: Wt[n][k], k<512 -> Wr[k][n], else Ws[k-512][n]
__global__ void wt_kernel(const float* __restrict__ Wr, const float* __restrict__ Ws,
                          unsigned short* __restrict__ Wt) {
  int idx = blockIdx.x * 256 + threadIdx.x;   // over 512*1024
  if (idx >= HD * K2) return;
  int n = idx >> 10;
  int k = idx & (K2 - 1);
  float v = (k < HD) ? Wr[k * HD + n] : Ws[(k - HD) * HD + n];
  Wt[idx] = f2bf(v);
}

// ---------------- fp32 -> bf16 convert with zero-padding past rows_in
__global__ void cvtpad_kernel(const float* __restrict__ in, unsigned short* __restrict__ out,
                              int rows_in, long long total4) {
  long long i = (long long)blockIdx.x * 256 + threadIdx.x;  // unit = 4 elements
  for (; i < total4; i += (long long)gridDim.x * 256) {
    int r = (int)((i * 4) >> 9);
    float4 v = make_float4(0.f, 0.f, 0.f, 0.f);
    if (r < rows_in) v = ((const float4*)in)[i];
    ushort4 o;
    o.x = f2bf(v.x); o.y = f2bf(v.y); o.z = f2bf(v.z); o.w = f2bf(v.w);
    ((ushort4*)out)[i] = o;
  }
}

// ---------------- CSR build: histogram, 3-phase scan, fill
__global__ void hist_kernel(const int* __restrict__ ei, int* __restrict__ deg) {
  int i = blockIdx.x * 256 + threadIdx.x;
  if (i < NE) atomicAdd(&deg[ei[NE + i]], 1);
}

// phase 1: per-block exclusive scan (LDS Hillis-Steele) + block totals
__global__ __launch_bounds__(256) void scan1_kernel(const int* __restrict__ deg,
                                                    int* __restrict__ tmp,
                                                    int* __restrict__ bsum) {
  __shared__ int sh[256];
  int t = threadIdx.x;
  int i = blockIdx.x * 256 + t;
  int v = (i < NN) ? deg[i] : 0;
  sh[t] = v;
  __syncthreads();
#pragma unroll
  for (int off = 1; off < 256; off <<= 1) {
    int u = (t >= off) ? sh[t - off] : 0;
    __syncthreads();
    sh[t] += u;
    __syncthreads();
  }
  if (i < NN) tmp[i] = sh[t] - v;          // exclusive within block
  if (t == 255) bsum[blockIdx.x] = sh[255];
}

// phase 2: scan the 196 block totals (one tiny block); also write row_ptr[NN]
__global__ __launch_bounds__(256) void scan2_kernel(int* __restrict__ bsum,
                                                    int* __restrict__ row_ptr) {
  __shared__ int sh[256];
  int t = threadIdx.x;
  int v = (t < SCAN_BLKS) ? bsum[t] : 0;
  sh[t] = v;
  __syncthreads();
#pragma unroll
  for (int off = 1; off < 256; off <<= 1) {
    int u = (t >= off) ? sh[t - off] : 0;
    __syncthreads();
    sh[t] += u;
    __syncthreads();
  }
  if (t < SCAN_BLKS) bsum[t] = sh[t] - v;  // exclusive block offsets, in place
  if (t == 255) row_ptr[NN] = sh[255];     // grand total
}

// phase 3: add block offsets -> row_ptr, cursor
__global__ __launch_bounds__(256) void scan3_kernel(const int* __restrict__ tmp,
                                                    const int* __restrict__ bsum,
                                                    int* __restrict__ row_ptr,
                                                    int* __restrict__ cursor) {
  int i = blockIdx.x * 256 + threadIdx.x;
  if (i < NN) {
    int r = tmp[i] + bsum[blockIdx.x];
    row_ptr[i] = r;
    cursor[i] = r;
  }
}

__global__ void fill_kernel(const int* __restrict__ ei, int* __restrict__ cursor,
                            int* __restrict__ col) {
  int i = blockIdx.x * 256 + threadIdx.x;
  if (i < NE) {
    int d = ei[NE + i];
    int p = atomicAdd(&cursor[d], 1);
    col[p] = ei[i];
  }
}

// ---------------- gather aggregation: out[n] = sum_{c in N(n)} X[c]  (bf16 in/out, fp32 acc)
// one wave per output row; lane covers 8 contiguous columns (64*8 = 512)
__global__ __launch_bounds__(256) void gather_kernel(const unsigned short* __restrict__ X,
                                                     const int* __restrict__ row_ptr,
                                                     const int* __restrict__ col,
                                                     unsigned short* __restrict__ out) {
  int w = (blockIdx.x * 256 + threadIdx.x) >> 6;  // wave id = output row
  int lane = threadIdx.x & 63;
  if (w >= MP) return;
  float a0 = 0.f, a1 = 0.f, a2 = 0.f, a3 = 0.f, a4 = 0.f, a5 = 0.f, a6 = 0.f, a7 = 0.f;
  if (w < NN) {
    int r0 = row_ptr[w], r1 = row_ptr[w + 1];
    for (int base = r0; base < r1; base += 64) {
      int idx = base + lane;
      int myc = (idx < r1) ? col[idx] : 0;
      int cnt = min(64, r1 - base);
      #pragma unroll 4
      for (int j = 0; j < cnt; j++) {
        int c = __shfl(myc, j);
        uint4 v = *(const uint4*)(X + (size_t)c * HD + lane * 8);
        a0 += bf2f((unsigned short)(v.x & 0xffff));
        a1 += bf2f((unsigned short)(v.x >> 16));
        a2 += bf2f((unsigned short)(v.y & 0xffff));
        a3 += bf2f((unsigned short)(v.y >> 16));
        a4 += bf2f((unsigned short)(v.z & 0xffff));
        a5 += bf2f((unsigned short)(v.z >> 16));
        a6 += bf2f((unsigned short)(v.w & 0xffff));
        a7 += bf2f((unsigned short)(v.w >> 16));
      }
    }
  }
  uint4 o;
  o.x = ((unsigned)f2bf(a1) << 16) | f2bf(a0);
  o.y = ((unsigned)f2bf(a3) << 16) | f2bf(a2);
  o.z = ((unsigned)f2bf(a5) << 16) | f2bf(a4);
  o.w = ((unsigned)f2bf(a7) << 16) | f2bf(a6);
  *(uint4*)(out + (size_t)w * HD + lane * 8) = o;
}

// ---------------- fused GEMM: H = relu([A0|A1] @ Wt^T + bias), all bf16 in, bf16 out
// A0,A1: [MP][512] bf16.  Wt: [512][1024] bf16 (row n = output col, contiguous K).
__global__ __launch_bounds__(256, 2) void gemm_kernel(
    const unsigned short* __restrict__ A0, const unsigned short* __restrict__ A1,
    const unsigned short* __restrict__ Wt, const float* __restrict__ bias,
    unsigned short* __restrict__ Hout) {
  __shared__ __align__(16) unsigned short Ads[128 * 64];
  __shared__ __align__(16) unsigned short Bds[128 * 64];

  const int tid = threadIdx.x;
  const int lane = tid & 63;
  const int wv = tid >> 6;   // 0..3
  const int wm = wv >> 1;    // 0..1
  const int wn = wv & 1;     // 0..1

  const int mt = blockIdx.x >> 2;   // 391 M-tiles
  const int nt = blockIdx.x & 3;    // 4 N-tiles
  const int row0 = mt * 128;
  const int col0 = nt * 128;

  f32x4 acc[4][4];
#pragma unroll
  for (int i = 0; i < 4; i++)
#pragma unroll
    for (int j = 0; j < 4; j++) acc[i][j] = (f32x4)(0.f);

  const int lr = lane >> 3;        // row within 8-row staging group
  const int lc = lane & 7;         // 16B chunk within 64-k row
  const int csw = lc ^ lr;         // pre-swizzled source chunk (T2 / m201 pattern)

  for (int kt = 0; kt < 16; ++kt) {
    const int k0 = kt * 64;
    const unsigned short* Asrc = (k0 < HD) ? A0 : A1;
    const int ka = k0 & (HD - 1);
#pragma unroll
    for (int it = 0; it < 4; ++it) {
      int r0 = (it * 4 + wv) * 8;
      g2l16(Asrc + (size_t)(row0 + r0 + lr) * HD + ka + csw * 8, &Ads[r0 * 64]);
    }
#pragma unroll
    for (int it = 0; it < 4; ++it) {
      int r0 = (it * 4 + wv) * 8;
      g2l16(Wt + (size_t)(col0 + r0 + lr) * K2 + k0 + csw * 8, &Bds[r0 * 64]);
    }
    __syncthreads();
#pragma unroll
    for (int kk = 0; kk < 2; ++kk) {
      bf16x8 af[4], bfr[4];
#pragma unroll
      for (int m = 0; m < 4; m++) {
        int r = wm * 64 + m * 16 + (lane & 15);
        int ck = (kk * 4 + (lane >> 4)) ^ (r & 7);
        af[m] = *(const bf16x8*)&Ads[r * 64 + ck * 8];
      }
#pragma unroll
      for (int n = 0; n < 4; n++) {
        int r = wn * 64 + n * 16 + (lane & 15);
        int ck = (kk * 4 + (lane >> 4)) ^ (r & 7);
        bfr[n] = *(const bf16x8*)&Bds[r * 64 + ck * 8];
      }
#pragma unroll
      for (int m = 0; m < 4; m++)
#pragma unroll
        for (int n = 0; n < 4; n++)
          acc[m][n] = __builtin_amdgcn_mfma_f32_16x16x32_bf16(af[m], bfr[n], acc[m][n], 0, 0, 0);
    }
    __syncthreads();
  }

#pragma unroll
  for (int n = 0; n < 4; n++) {
    int c = col0 + wn * 64 + n * 16 + (lane & 15);
    float bv = bias[c];
#pragma unroll
    for (int m = 0; m < 4; m++) {
      int rbase = row0 + wm * 64 + m * 16 + (lane >> 4) * 4;
#pragma unroll
      for (int r = 0; r < 4; r++) {
        float v = acc[m][n][r] + bv;
        v = v > 0.f ? v : 0.f;
        Hout[(size_t)(rbase + r) * HD + c] = f2bf(v);
      }
    }
  }
}

// ---------------- mean-pool partial sums (batch is sorted; binary search boundaries)
__device__ __forceinline__ int lbound(const int* b, int v) {
  int lo = 0, hi = NN;
  while (lo < hi) { int m = (lo + hi) >> 1; if (b[m] < v) lo = m + 1; else hi = m; }
  return lo;
}

__global__ void pool_kernel(const unsigned short* __restrict__ H, const int* __restrict__ batch,
                            float* __restrict__ pooled) {
  int b = blockIdx.x;          // 64 graphs * 2 col-halves * 8 row-chunks
  int g = b >> 4;
  int half = (b >> 3) & 1;
  int chunk = b & 7;
  int col = half * 256 + threadIdx.x;
  int start = lbound(batch, g);
  int end = lbound(batch, g + 1);
  int len = end - start;
  int r0 = start + (int)(((long long)len * chunk) >> 3);
  int r1 = start + (int)(((long long)len * (chunk + 1)) >> 3);
  float s = 0.f;
  for (int r = r0; r < r1; r++) s += bf2f(H[(size_t)r * HD + col]);
  atomicAdd(&pooled[g * HD + col], s);
}

// ---------------- classifier: out[g][c] = relu(pooled/cnt) @ Wl + bl
__global__ void final_kernel(const float* __restrict__ pooled, const int* __restrict__ batch,
                             const float* __restrict__ Wl, const float* __restrict__ bl,
                             float* __restrict__ out) {
  int g = blockIdx.x;
  int t = threadIdx.x;   // 256
  int lane = t & 63, wv = t >> 6;
  int start = lbound(batch, g);
  int end = lbound(batch, g + 1);
  float cnt = (float)(end - start);
  if (cnt < 1.f) cnt = 1.f;
  float a[10];
#pragma unroll
  for (int c = 0; c < 10; c++) a[c] = 0.f;
  for (int n = t; n < HD; n += 256) {
    float p = pooled[g * HD + n] / cnt;
    p = p > 0.f ? p : 0.f;
#pragma unroll
    for (int c = 0; c < 10; c++) a[c] += p * Wl[n * 10 + c];
  }
  __shared__ float red[10][4];
#pragma unroll
  for (int c = 0; c < 10; c++) {
    float v = a[c];
#pragma unroll
    for (int off = 32; off >= 1; off >>= 1) v += __shfl_down(v, off);
    if (lane == 0) red[c][wv] = v;
  }
  __syncthreads();
  if (t < 10) out[g * 10 + t] = red[t][0] + red[t][1] + red[t][2] + red[t][3] + bl[t];
}

extern "C" void kernel_launch(void* const* d_in, const int* in_sizes, int n_in,
                              void* d_out, int out_size, void* d_ws, size_t ws_size,
                              hipStream_t stream) {
  const float* x   = (const float*)d_in[0];
  const int* ei    = (const int*)d_in[1];
  const int* batch = (const int*)d_in[2];
  const float* Wr0 = (const float*)d_in[3];
  const float* br0 = (const float*)d_in[4];
  const float* Ws0 = (const float*)d_in[5];
  const float* Wr1 = (const float*)d_in[6];
  const float* br1 = (const float*)d_in[7];
  const float* Ws1 = (const float*)d_in[8];
  const float* Wl  = (const float*)d_in[9];
  const float* bl  = (const float*)d_in[10];
  float* out = (float*)d_out;

  char* ws = (char*)d_ws;
  size_t off = 0;
  auto alloc = [&](size_t bytes) { char* p = ws + off; off += (bytes + 255) & ~255ULL; return p; };
  unsigned short* xb   = (unsigned short*)alloc((size_t)MP * HD * 2);
  unsigned short* h0   = (unsigned short*)alloc((size_t)MP * HD * 2);
  unsigned short* aggb = (unsigned short*)alloc((size_t)MP * HD * 2);
  unsigned short* Wt0  = (unsigned short*)alloc((size_t)HD * K2 * 2);
  unsigned short* Wt1  = (unsigned short*)alloc((size_t)HD * K2 * 2);
  float* pooled        = (float*)alloc((size_t)GG * HD * 4);
  int* deg             = (int*)alloc((size_t)NN * 4);
  int* row_ptr         = (int*)alloc((size_t)(NN + 1) * 4);
  int* cursor          = (int*)alloc((size_t)NN * 4);
  int* col             = (int*)alloc((size_t)NE * 4);
  int* stmp            = (int*)alloc((size_t)NN * 4);
  int* bsum            = (int*)alloc((size_t)256 * 4);
  unsigned short* h1 = xb;  // reuse: xb dead after GEMM1 consumes it

  const long long totMP4 = (long long)MP * HD / 4;

  // CSR build
  hipMemsetAsync(deg, 0, (size_t)NN * 4, stream);
  hist_kernel<<<(NE + 255) / 256, 256, 0, stream>>>(ei, deg);
  scan1_kernel<<<SCAN_BLKS, 256, 0, stream>>>(deg, stmp, bsum);
  scan2_kernel<<<1, 256, 0, stream>>>(bsum, row_ptr);
  scan3_kernel<<<SCAN_BLKS, 256, 0, stream>>>(stmp, bsum, row_ptr, cursor);
  fill_kernel<<<(NE + 255) / 256, 256, 0, stream>>>(ei, cursor, col);

  // weights + input conversion
  wt_kernel<<<2048, 256, 0, stream>>>(Wr0, Ws0, Wt0);
  wt_kernel<<<2048, 256, 0, stream>>>(Wr1, Ws1, Wt1);
  cvtpad_kernel<<<2048, 256, 0, stream>>>(x, xb, NN, totMP4);

  // layer 0
  gather_kernel<<<MP / 4, 256, 0, stream>>>(xb, row_ptr, col, aggb);
  gemm_kernel<<<391 * 4, 256, 0, stream>>>(aggb, xb, Wt0, br0, h0);

  // layer 1
  gather_kernel<<<MP / 4, 256, 0, stream>>>(h0, row_ptr, col, aggb);
  gemm_kernel<<<391 * 4, 256, 0, stream>>>(aggb, h0, Wt1, br1, h1);

  // pool + classify
  hipMemsetAsync(pooled, 0, (size_t)GG * HD * 4, stream);
  pool_kernel<<<GG * 16, 256, 0, stream>>>(h1, batch, pooled);
  final_kernel<<<GG, 256, 0, stream>>>(pooled, batch, Wl, bl, out);
}

// Round 4
// 667.645 us; speedup vs baseline: 33.1229x; 1.0264x over previous
//
#include <hip/hip_runtime.h>

// Problem constants
#define NN 50000      // nodes
#define NE 800000     // edges
#define MP 50048      // padded rows = 391*128
#define GG 64         // graphs
#define HD 512        // hidden/feature dim
#define K2 1024       // fused K (agg | self)
#define SCAN_BLKS 196 // ceil(50000/256)

typedef __attribute__((ext_vector_type(8))) short bf16x8;
typedef __attribute__((ext_vector_type(4))) float f32x4;

__device__ __forceinline__ unsigned short f2bf(float f) {
  unsigned u = __builtin_bit_cast(unsigned, f);
  u += 0x7fffu + ((u >> 16) & 1u);
  return (unsigned short)(u >> 16);
}
__device__ __forceinline__ float bf2f(unsigned short h) {
  unsigned u = ((unsigned)h) << 16;
  return __builtin_bit_cast(float, u);
}

__device__ __forceinline__ void g2l16(const void* g, void* l) {
  __builtin_amdgcn_global_load_lds(
      (const __attribute__((address_space(1))) unsigned int*)g,
      (__attribute__((address_space(3))) unsigned int*)l, 16, 0, 0);
}

// ---------------- weight transpose+convert: Wt[n][k], k<512 -> Wr[k][n], else Ws[k-512][n]
__global__ void wt_kernel(const float* __restrict__ Wr, const float* __restrict__ Ws,
                          unsigned short* __restrict__ Wt) {
  int idx = blockIdx.x * 256 + threadIdx.x;   // over 512*1024
  if (idx >= HD * K2) return;
  int n = idx >> 10;
  int k = idx & (K2 - 1);
  float v = (k < HD) ? Wr[k * HD + n] : Ws[(k - HD) * HD + n];
  Wt[idx] = f2bf(v);
}

// ---------------- fp32 -> bf16 convert with zero-padding past rows_in
__global__ void cvtpad_kernel(const float* __restrict__ in, unsigned short* __restrict__ out,
                              int rows_in, long long total4) {
  long long i = (long long)blockIdx.x * 256 + threadIdx.x;  // unit = 4 elements
  for (; i < total4; i += (long long)gridDim.x * 256) {
    int r = (int)((i * 4) >> 9);
    float4 v = make_float4(0.f, 0.f, 0.f, 0.f);
    if (r < rows_in) v = ((const float4*)in)[i];
    ushort4 o;
    o.x = f2bf(v.x); o.y = f2bf(v.y); o.z = f2bf(v.z); o.w = f2bf(v.w);
    ((ushort4*)out)[i] = o;
  }
}

// ---------------- CSR build: histogram, 3-phase scan, fill
__global__ void hist_kernel(const int* __restrict__ ei, int* __restrict__ deg) {
  int i = blockIdx.x * 256 + threadIdx.x;
  if (i < NE) atomicAdd(&deg[ei[NE + i]], 1);
}

// phase 1: per-block exclusive scan (LDS Hillis-Steele) + block totals
__global__ __launch_bounds__(256) void scan1_kernel(const int* __restrict__ deg,
                                                    int* __restrict__ tmp,
                                                    int* __restrict__ bsum) {
  __shared__ int sh[256];
  int t = threadIdx.x;
  int i = blockIdx.x * 256 + t;
  int v = (i < NN) ? deg[i] : 0;
  sh[t] = v;
  __syncthreads();
#pragma unroll
  for (int off = 1; off < 256; off <<= 1) {
    int u = (t >= off) ? sh[t - off] : 0;
    __syncthreads();
    sh[t] += u;
    __syncthreads();
  }
  if (i < NN) tmp[i] = sh[t] - v;          // exclusive within block
  if (t == 255) bsum[blockIdx.x] = sh[255];
}

// phase 2: scan the 196 block totals (one tiny block); also write row_ptr[NN]
__global__ __launch_bounds__(256) void scan2_kernel(int* __restrict__ bsum,
                                                    int* __restrict__ row_ptr) {
  __shared__ int sh[256];
  int t = threadIdx.x;
  int v = (t < SCAN_BLKS) ? bsum[t] : 0;
  sh[t] = v;
  __syncthreads();
#pragma unroll
  for (int off = 1; off < 256; off <<= 1) {
    int u = (t >= off) ? sh[t - off] : 0;
    __syncthreads();
    sh[t] += u;
    __syncthreads();
  }
  if (t < SCAN_BLKS) bsum[t] = sh[t] - v;  // exclusive block offsets, in place
  if (t == 255) row_ptr[NN] = sh[255];     // grand total
}

// phase 3: add block offsets -> row_ptr, cursor
__global__ __launch_bounds__(256) void scan3_kernel(const int* __restrict__ tmp,
                                                    const int* __restrict__ bsum,
                                                    int* __restrict__ row_ptr,
                                                    int* __restrict__ cursor) {
  int i = blockIdx.x * 256 + threadIdx.x;
  if (i < NN) {
    int r = tmp[i] + bsum[blockIdx.x];
    row_ptr[i] = r;
    cursor[i] = r;
  }
}

__global__ void fill_kernel(const int* __restrict__ ei, int* __restrict__ cursor,
                            int* __restrict__ col) {
  int i = blockIdx.x * 256 + threadIdx.x;
  if (i < NE) {
    int d = ei[NE + i];
    int p = atomicAdd(&cursor[d], 1);
    col[p] = ei[i];
  }
}

// ---------------- gather aggregation: out[n] = sum_{c in N(n)} X[c]  (bf16 in/out, fp32 acc)
// one wave per output row; lane covers 8 contiguous columns (64*8 = 512)
__global__ __launch_bounds__(256) void gather_kernel(const unsigned short* __restrict__ X,
                                                     const int* __restrict__ row_ptr,
                                                     const int* __restrict__ col,
                                                     unsigned short* __restrict__ out) {
  int w = (blockIdx.x * 256 + threadIdx.x) >> 6;  // wave id = output row
  int lane = threadIdx.x & 63;
  if (w >= MP) return;
  float a0 = 0.f, a1 = 0.f, a2 = 0.f, a3 = 0.f, a4 = 0.f, a5 = 0.f, a6 = 0.f, a7 = 0.f;
  if (w < NN) {
    int r0 = row_ptr[w], r1 = row_ptr[w + 1];
    for (int base = r0; base < r1; base += 64) {
      int idx = base + lane;
      int myc = (idx < r1) ? col[idx] : 0;
      int cnt = min(64, r1 - base);
      #pragma unroll 8
      for (int j = 0; j < cnt; j++) {
        int c = __shfl(myc, j);
        uint4 v = *(const uint4*)(X + (size_t)c * HD + lane * 8);
        a0 += bf2f((unsigned short)(v.x & 0xffff));
        a1 += bf2f((unsigned short)(v.x >> 16));
        a2 += bf2f((unsigned short)(v.y & 0xffff));
        a3 += bf2f((unsigned short)(v.y >> 16));
        a4 += bf2f((unsigned short)(v.z & 0xffff));
        a5 += bf2f((unsigned short)(v.z >> 16));
        a6 += bf2f((unsigned short)(v.w & 0xffff));
        a7 += bf2f((unsigned short)(v.w >> 16));
      }
    }
  }
  uint4 o;
  o.x = ((unsigned)f2bf(a1) << 16) | f2bf(a0);
  o.y = ((unsigned)f2bf(a3) << 16) | f2bf(a2);
  o.z = ((unsigned)f2bf(a5) << 16) | f2bf(a4);
  o.w = ((unsigned)f2bf(a7) << 16) | f2bf(a6);
  *(uint4*)(out + (size_t)w * HD + lane * 8) = o;
}

// ---------------- fused GEMM v2: H = relu([A0|A1] @ Wt^T + bias)
// BM=128, BN=256, BK=64, 512 threads (8 waves, wave grid 2M x 4N, 64x64 per wave).
// A0,A1: [MP][512] bf16.  Wt: [512][1024] bf16 (row n = output col, contiguous K).
__global__ __launch_bounds__(512, 2) void gemm_kernel(
    const unsigned short* __restrict__ A0, const unsigned short* __restrict__ A1,
    const unsigned short* __restrict__ Wt, const float* __restrict__ bias,
    unsigned short* __restrict__ Hout) {
  __shared__ __align__(16) unsigned short Ads[128 * 64];
  __shared__ __align__(16) unsigned short Bds[256 * 64];

  const int tid = threadIdx.x;
  const int lane = tid & 63;
  const int wv = tid >> 6;   // 0..7
  const int wm = wv >> 2;    // 0..1  (64-row slice)
  const int wn = wv & 3;     // 0..3  (64-col slice)

  // bijective XCD-chunk swizzle (m204): keep the nt-pair of one mt on one XCD
  const int nwg = 782;                 // 391 mt * 2 nt
  const int orig = blockIdx.x;
  const int q = nwg >> 3, r8 = nwg & 7;
  const int xcd = orig & 7;
  const int wgid = (xcd < r8 ? xcd * (q + 1) : r8 * (q + 1) + (xcd - r8) * q) + (orig >> 3);

  const int mt = wgid >> 1;        // 0..390
  const int nt = wgid & 1;         // 0..1
  const int row0 = mt * 128;
  const int col0 = nt * 256;

  f32x4 acc[4][4];
#pragma unroll
  for (int i = 0; i < 4; i++)
#pragma unroll
    for (int j = 0; j < 4; j++) acc[i][j] = (f32x4)(0.f);

  const int lr = lane >> 3;        // row within 8-row staging group
  const int lc = lane & 7;         // 16B chunk within 64-k row
  const int csw = lc ^ lr;         // pre-swizzled source chunk (T2 / m201 pattern)

  for (int kt = 0; kt < 16; ++kt) {
    const int k0 = kt * 64;
    const unsigned short* Asrc = (k0 < HD) ? A0 : A1;
    const int ka = k0 & (HD - 1);
    // A: 128 rows = 2 rounds of (8 waves x 8 rows)
#pragma unroll
    for (int it = 0; it < 2; ++it) {
      int rg = it * 8 + wv;   // 0..15
      g2l16(Asrc + (size_t)(row0 + rg * 8 + lr) * HD + ka + csw * 8, &Ads[rg * 8 * 64]);
    }
    // B: 256 rows = 4 rounds
#pragma unroll
    for (int it = 0; it < 4; ++it) {
      int rg = it * 8 + wv;   // 0..31
      g2l16(Wt + (size_t)(col0 + rg * 8 + lr) * K2 + k0 + csw * 8, &Bds[rg * 8 * 64]);
    }
    __syncthreads();
#pragma unroll
    for (int kk = 0; kk < 2; ++kk) {
      bf16x8 af[4], bfr[4];
#pragma unroll
      for (int m = 0; m < 4; m++) {
        int r = wm * 64 + m * 16 + (lane & 15);
        int ck = (kk * 4 + (lane >> 4)) ^ (r & 7);
        af[m] = *(const bf16x8*)&Ads[r * 64 + ck * 8];
      }
#pragma unroll
      for (int n = 0; n < 4; n++) {
        int r = wn * 64 + n * 16 + (lane & 15);
        int ck = (kk * 4 + (lane >> 4)) ^ (r & 7);
        bfr[n] = *(const bf16x8*)&Bds[r * 64 + ck * 8];
      }
#pragma unroll
      for (int m = 0; m < 4; m++)
#pragma unroll
        for (int n = 0; n < 4; n++)
          acc[m][n] = __builtin_amdgcn_mfma_f32_16x16x32_bf16(af[m], bfr[n], acc[m][n], 0, 0, 0);
    }
    __syncthreads();
  }

#pragma unroll
  for (int n = 0; n < 4; n++) {
    int c = col0 + wn * 64 + n * 16 + (lane & 15);
    float bv = bias[c];
#pragma unroll
    for (int m = 0; m < 4; m++) {
      int rbase = row0 + wm * 64 + m * 16 + (lane >> 4) * 4;
#pragma unroll
      for (int r = 0; r < 4; r++) {
        float v = acc[m][n][r] + bv;
        v = v > 0.f ? v : 0.f;
        Hout[(size_t)(rbase + r) * HD + c] = f2bf(v);
      }
    }
  }
}

// ---------------- mean-pool partial sums (batch is sorted; binary search boundaries)
__device__ __forceinline__ int lbound(const int* b, int v) {
  int lo = 0, hi = NN;
  while (lo < hi) { int m = (lo + hi) >> 1; if (b[m] < v) lo = m + 1; else hi = m; }
  return lo;
}

__global__ void pool_kernel(const unsigned short* __restrict__ H, const int* __restrict__ batch,
                            float* __restrict__ pooled) {
  int b = blockIdx.x;          // 64 graphs * 2 col-halves * 8 row-chunks
  int g = b >> 4;
  int half = (b >> 3) & 1;
  int chunk = b & 7;
  int col = half * 256 + threadIdx.x;
  int start = lbound(batch, g);
  int end = lbound(batch, g + 1);
  int len = end - start;
  int r0 = start + (int)(((long long)len * chunk) >> 3);
  int r1 = start + (int)(((long long)len * (chunk + 1)) >> 3);
  float s = 0.f;
  for (int r = r0; r < r1; r++) s += bf2f(H[(size_t)r * HD + col]);
  atomicAdd(&pooled[g * HD + col], s);
}

// ---------------- classifier: out[g][c] = relu(pooled/cnt) @ Wl + bl
__global__ void final_kernel(const float* __restrict__ pooled, const int* __restrict__ batch,
                             const float* __restrict__ Wl, const float* __restrict__ bl,
                             float* __restrict__ out) {
  int g = blockIdx.x;
  int t = threadIdx.x;   // 256
  int lane = t & 63, wv = t >> 6;
  int start = lbound(batch, g);
  int end = lbound(batch, g + 1);
  float cnt = (float)(end - start);
  if (cnt < 1.f) cnt = 1.f;
  float a[10];
#pragma unroll
  for (int c = 0; c < 10; c++) a[c] = 0.f;
  for (int n = t; n < HD; n += 256) {
    float p = pooled[g * HD + n] / cnt;
    p = p > 0.f ? p : 0.f;
#pragma unroll
    for (int c = 0; c < 10; c++) a[c] += p * Wl[n * 10 + c];
  }
  __shared__ float red[10][4];
#pragma unroll
  for (int c = 0; c < 10; c++) {
    float v = a[c];
#pragma unroll
    for (int off = 32; off >= 1; off >>= 1) v += __shfl_down(v, off);
    if (lane == 0) red[c][wv] = v;
  }
  __syncthreads();
  if (t < 10) out[g * 10 + t] = red[t][0] + red[t][1] + red[t][2] + red[t][3] + bl[t];
}

extern "C" void kernel_launch(void* const* d_in, const int* in_sizes, int n_in,
                              void* d_out, int out_size, void* d_ws, size_t ws_size,
                              hipStream_t stream) {
  const float* x   = (const float*)d_in[0];
  const int* ei    = (const int*)d_in[1];
  const int* batch = (const int*)d_in[2];
  const float* Wr0 = (const float*)d_in[3];
  const float* br0 = (const float*)d_in[4];
  const float* Ws0 = (const float*)d_in[5];
  const float* Wr1 = (const float*)d_in[6];
  const float* br1 = (const float*)d_in[7];
  const float* Ws1 = (const float*)d_in[8];
  const float* Wl  = (const float*)d_in[9];
  const float* bl  = (const float*)d_in[10];
  float* out = (float*)d_out;

  char* ws = (char*)d_ws;
  size_t off = 0;
  auto alloc = [&](size_t bytes) { char* p = ws + off; off += (bytes + 255) & ~255ULL; return p; };
  unsigned short* xb   = (unsigned short*)alloc((size_t)MP * HD * 2);
  unsigned short* h0   = (unsigned short*)alloc((size_t)MP * HD * 2);
  unsigned short* aggb = (unsigned short*)alloc((size_t)MP * HD * 2);
  unsigned short* Wt0  = (unsigned short*)alloc((size_t)HD * K2 * 2);
  unsigned short* Wt1  = (unsigned short*)alloc((size_t)HD * K2 * 2);
  float* pooled        = (float*)alloc((size_t)GG * HD * 4);
  int* deg             = (int*)alloc((size_t)NN * 4);
  int* row_ptr         = (int*)alloc((size_t)(NN + 1) * 4);
  int* cursor          = (int*)alloc((size_t)NN * 4);
  int* col             = (int*)alloc((size_t)NE * 4);
  int* stmp            = (int*)alloc((size_t)NN * 4);
  int* bsum            = (int*)alloc((size_t)256 * 4);
  unsigned short* h1 = xb;  // reuse: xb dead after GEMM1 consumes it

  const long long totMP4 = (long long)MP * HD / 4;

  // CSR build
  hipMemsetAsync(deg, 0, (size_t)NN * 4, stream);
  hist_kernel<<<(NE + 255) / 256, 256, 0, stream>>>(ei, deg);
  scan1_kernel<<<SCAN_BLKS, 256, 0, stream>>>(deg, stmp, bsum);
  scan2_kernel<<<1, 256, 0, stream>>>(bsum, row_ptr);
  scan3_kernel<<<SCAN_BLKS, 256, 0, stream>>>(stmp, bsum, row_ptr, cursor);
  fill_kernel<<<(NE + 255) / 256, 256, 0, stream>>>(ei, cursor, col);

  // weights + input conversion
  wt_kernel<<<2048, 256, 0, stream>>>(Wr0, Ws0, Wt0);
  wt_kernel<<<2048, 256, 0, stream>>>(Wr1, Ws1, Wt1);
  cvtpad_kernel<<<2048, 256, 0, stream>>>(x, xb, NN, totMP4);

  // layer 0
  gather_kernel<<<MP / 4, 256, 0, stream>>>(xb, row_ptr, col, aggb);
  gemm_kernel<<<391 * 2, 512, 0, stream>>>(aggb, xb, Wt0, br0, h0);

  // layer 1
  gather_kernel<<<MP / 4, 256, 0, stream>>>(h0, row_ptr, col, aggb);
  gemm_kernel<<<391 * 2, 512, 0, stream>>>(aggb, h0, Wt1, br1, h1);

  // pool + classify
  hipMemsetAsync(pooled, 0, (size_t)GG * HD * 4, stream);
  pool_kernel<<<GG * 16, 256, 0, stream>>>(h1, batch, pooled);
  final_kernel<<<GG, 256, 0, stream>>>(pooled, batch, Wl, bl, out);
}